// Round 11
// baseline (206.002 us; speedup 1.0000x reference)
//
#include <hip/hip_runtime.h>
#include <hip/hip_bf16.h>
#include <cmath>

#define N_NODES 50000
#define N_EDGES 800000
#define D_IN 256
#define D_HID 128
#define D_ENC 64
#define NBUK 128         // dest buckets, bucket = c >> 9 (98 used)
#define BSH 9
#define BMSK 511
#define BCAP 16384       // fixed bucket capacity (expected ~8.2K, huge margin)
#define PB_EPT 8         // edges per thread in part_k
#define NVBUK 98         // buckets covering N_NODES
#define PSLOTS (NVBUK * 512)   // 50176 perm slots

typedef short short8 __attribute__((ext_vector_type(8)));
typedef float floatx4 __attribute__((ext_vector_type(4)));
typedef float floatx8 __attribute__((ext_vector_type(8)));
typedef unsigned short ushort8v __attribute__((ext_vector_type(8)));

static __device__ __forceinline__ unsigned short f2bf(float f) {
    unsigned int u = __float_as_uint(f);
    unsigned int r = (u + 0x7FFFu + ((u >> 16) & 1u)) >> 16;   // RNE
    return (unsigned short)r;
}
static __device__ __forceinline__ float bf2f(unsigned short u) {
    return __uint_as_float(((unsigned int)u) << 16);
}
static __device__ __forceinline__ floatx8 bf2f8(ushort8v u) {
    floatx8 f;
#pragma unroll
    for (int j = 0; j < 8; ++j) f[j] = bf2f(u[j]);
    return f;
}

// ---------------- W pre-swizzle into B-fragment layout (bf16) ----------------
static __device__ __forceinline__ void wswz(const float* __restrict__ W,
                                            unsigned short* __restrict__ Wsw,
                                            int t, int K, int N) {
    int KS = K / 32;
    int lane = t & 63;
    int ks   = (t >> 6) % KS;
    int ct   = (t >> 6) / KS;
    int m = lane & 15, quad = lane >> 4;
    int kbase = ks * 32 + quad * 8;
    int col   = ct * 16 + m;
#pragma unroll
    for (int j = 0; j < 8; ++j)
        Wsw[t * 8 + j] = f2bf(W[(size_t)(kbase + j) * N + col]);
}

// ---------------- radix partition (+fused weight swizzle) ----------------
// rec = (src << 9) | (dst & 511); bucket b occupies [b*BCAP, b*BCAP + count).
// bcur holds per-bucket COUNTS (memset to 0 before launch).
__global__ void part_k(const int* __restrict__ rows, const int* __restrict__ cols,
                       int* __restrict__ bcur, unsigned int* __restrict__ brecs,
                       const float* __restrict__ W1, const float* __restrict__ W2,
                       unsigned short* __restrict__ Wsw1, unsigned short* __restrict__ Wsw2) {
    __shared__ int h[NBUK], base[NBUK];
    // fused weight swizzle on the first 20 blocks
    int t = blockIdx.x * blockDim.x + threadIdx.x;
    if (t < 4096) wswz(W1, Wsw1, t, D_IN, D_HID);
    else if (t < 5120) wswz(W2, Wsw2, t - 4096, D_HID, D_ENC);

    int e0 = blockIdx.x * (256 * PB_EPT);
    if (threadIdx.x < NBUK) h[threadIdx.x] = 0;
    __syncthreads();
    int src[PB_EPT], dst[PB_EPT];
#pragma unroll
    for (int j = 0; j < PB_EPT; ++j) {
        int e = e0 + j * 256 + threadIdx.x;
        if (e < N_EDGES) {
            src[j] = rows[e]; dst[j] = cols[e];
            atomicAdd(&h[dst[j] >> BSH], 1);
        } else dst[j] = -1;
    }
    __syncthreads();
    if (threadIdx.x < NBUK) {
        int c = h[threadIdx.x];
        base[threadIdx.x] = threadIdx.x * BCAP + (c ? atomicAdd(&bcur[threadIdx.x], c) : 0);
        h[threadIdx.x] = 0;
    }
    __syncthreads();
#pragma unroll
    for (int j = 0; j < PB_EPT; ++j) {
        if (dst[j] >= 0) {
            int b = dst[j] >> BSH;
            int r = base[b] + atomicAdd(&h[b], 1);
            if (r < (b + 1) * BCAP)   // overflow guard (never hit for this input)
                brecs[r] = ((unsigned int)src[j] << BSH) | (unsigned int)(dst[j] & BMSK);
        }
    }
}

// ---------------- per-bucket CSR + block-local degree sort (perm) ----------------
__global__ __launch_bounds__(512) void bucket_csr_k(const unsigned int* __restrict__ brecs,
                                                    const int* __restrict__ bcur,
                                                    int* __restrict__ rowptr,
                                                    int* __restrict__ rowcnt,
                                                    int* __restrict__ srcs,
                                                    float* __restrict__ dinv,
                                                    int* __restrict__ perm) {
    __shared__ int s[512];
    __shared__ int cur[512];
    __shared__ int dh[64], db[64];
    int b = blockIdx.x;
    int cb = bcur[b]; if (cb > BCAP) cb = BCAP;
    int ebeg = b * BCAP, eend = ebeg + cb;
    int tid = threadIdx.x;
    s[tid] = 0;
    if (tid < 64) dh[tid] = 0;
    __syncthreads();
    for (int e = ebeg + tid; e < eend; e += 512)
        atomicAdd(&s[brecs[e] & BMSK], 1);
    __syncthreads();
    int v = s[tid];
    for (int off = 1; off < 512; off <<= 1) {
        int t = (tid >= off) ? s[tid - off] : 0;
        __syncthreads();
        s[tid] += t;
        __syncthreads();
    }
    int excl = s[tid] - v;
    cur[tid] = excl;
    int node = (b << BSH) + tid;
    bool valid = node < N_NODES;
    int dcl = v > 63 ? 63 : v;
    perm[(b << BSH) + tid] = -1;           // default: empty slot
    if (valid) {
        rowptr[node] = ebeg + excl;
        rowcnt[node] = v;
        dinv[node] = rsqrtf((float)(v + 1));   // +1 self-loop
        atomicAdd(&dh[dcl], 1);                // degree histogram
    }
    __syncthreads();
    if (tid == 0) {                            // 64-bin exclusive scan
        int a = 0;
        for (int i = 0; i < 64; ++i) { int c = dh[i]; db[i] = a; a += c; dh[i] = 0; }
    }
    __syncthreads();
    if (valid) {                               // degree-sorted placement
        int pos = db[dcl] + atomicAdd(&dh[dcl], 1);
        perm[(b << BSH) + pos] = node;
    }
    for (int e = ebeg + tid; e < eend; e += 512) {
        unsigned int rec = brecs[e];
        int p = atomicAdd(&cur[rec & BMSK], 1);
        srcs[ebeg + p] = (int)(rec >> BSH);
    }
}

// ---------------- MFMA GEMM: H[r,:] = bf16(dinv[r] * (X[r,:] @ W)) ----------------
template<int K, int N, bool IN_BF16>
__global__ __launch_bounds__(256) void gemm_mfma_k(const void* __restrict__ Xv,
                                                   const unsigned short* __restrict__ Wsw,
                                                   const float* __restrict__ dinv,
                                                   unsigned short* __restrict__ H, int n) {
    constexpr int KS = K / 32, CT = N / 16, KP = K + 8;
    __shared__ unsigned short As[64 * KP];
    int row0 = blockIdx.x * 64;
    if (IN_BF16) {
        const ushort8v* X8 = (const ushort8v*)Xv;
        constexpr int NF8 = 64 * (K / 8);
        for (int idx = threadIdx.x; idx < NF8; idx += 256) {
            int r = idx / (K / 8), c8 = idx % (K / 8);
            int gr = row0 + r;
            ushort8v v = (gr < n) ? X8[(size_t)gr * (K / 8) + c8] : (ushort8v)0;
            *(ushort8v*)&As[r * KP + c8 * 8] = v;
        }
    } else {
        const float4* X4 = (const float4*)Xv;
        constexpr int NF4 = 64 * (K / 4);
        for (int idx = threadIdx.x; idx < NF4; idx += 256) {
            int r = idx / (K / 4), c4 = idx % (K / 4);
            int gr = row0 + r;
            float4 v = (gr < n) ? X4[(size_t)gr * (K / 4) + c4] : float4{0, 0, 0, 0};
            __hip_bfloat162 p0 = __float22bfloat162_rn(float2{v.x, v.y});   // packed RNE cvt
            __hip_bfloat162 p1 = __float22bfloat162_rn(float2{v.z, v.w});
            uint2 u; u.x = *(unsigned int*)&p0; u.y = *(unsigned int*)&p1;
            *(uint2*)&As[r * KP + c4 * 4] = u;
        }
    }
    __syncthreads();

    int w    = threadIdx.x >> 6;
    int lane = threadIdx.x & 63;
    int m    = lane & 15;
    int quad = lane >> 4;

    floatx4 acc[CT];
#pragma unroll
    for (int ct = 0; ct < CT; ++ct)
#pragma unroll
        for (int i = 0; i < 4; ++i) acc[ct][i] = 0.0f;

#pragma unroll
    for (int ks = 0; ks < KS; ++ks) {
        short8 af = *(const short8*)&As[(w * 16 + m) * KP + ks * 32 + quad * 8];
#pragma unroll
        for (int ct = 0; ct < CT; ++ct) {
            short8 bf = *(const short8*)&Wsw[(size_t)((ct * KS + ks) * 64 + lane) * 8];
            acc[ct] = __builtin_amdgcn_mfma_f32_16x16x32_bf16(af, bf, acc[ct], 0, 0, 0);
        }
    }

    int rbase = row0 + w * 16 + quad * 4;
    float dv[4];
#pragma unroll
    for (int reg = 0; reg < 4; ++reg) {
        int r = rbase + reg;
        dv[reg] = (r < n) ? dinv[r] : 0.0f;
    }
#pragma unroll
    for (int ct = 0; ct < CT; ++ct)
#pragma unroll
        for (int reg = 0; reg < 4; ++reg) {
            int r = rbase + reg;
            if (r < n) H[(size_t)r * N + ct * 16 + m] = f2bf(acc[ct][reg] * dv[reg]);
        }
}

// ---------------- fused gather1 + gemm2 (degree-equalized via perm) ----------------
// Block = 256 (4 waves), 16 perm slots/block CONCURRENT (16 lanes/node, x4 chains).
// Rows -> LDS A-tile; phase 2: MFMA 16x128 @ 128x64, wave w = col-tile w;
// stores scatter through nid[].
__global__ __launch_bounds__(256) void g1g2_k(const ushort8v* __restrict__ hs,
                                              const int* __restrict__ rowptr,
                                              const int* __restrict__ rowcnt,
                                              const int* __restrict__ srcs,
                                              const float* __restrict__ dinv,
                                              const float4* __restrict__ b1_4,
                                              const unsigned short* __restrict__ Wsw2,
                                              const int* __restrict__ perm,
                                              unsigned short* __restrict__ h2) {
    constexpr int KP = D_HID + 8;   // 136
    __shared__ unsigned short As[16 * KP];
    __shared__ int nid[16];
    int slotb = blockIdx.x * 16;
    int ln = threadIdx.x >> 4;      // local slot 0..15
    int d8 = threadIdx.x & 15;
    int node = perm[slotb + ln];
    if (d8 == 0) nid[ln] = node;
    if (node >= 0) {
        int beg = rowptr[node];
        int end = beg + rowcnt[node];
        floatx8 a0 = {0,0,0,0,0,0,0,0}, a1 = a0, a2 = a0, a3 = a0;
        int i = beg;
        for (; i + 4 <= end; i += 4) {
            int s0 = srcs[i], s1 = srcs[i + 1], s2 = srcs[i + 2], s3 = srcs[i + 3];
            a0 += bf2f8(hs[(size_t)s0 * 16 + d8]);
            a1 += bf2f8(hs[(size_t)s1 * 16 + d8]);
            a2 += bf2f8(hs[(size_t)s2 * 16 + d8]);
            a3 += bf2f8(hs[(size_t)s3 * 16 + d8]);
        }
        for (; i < end; ++i)
            a0 += bf2f8(hs[(size_t)srcs[i] * 16 + d8]);
        floatx8 acc = a0 + a1 + a2 + a3 + bf2f8(hs[(size_t)node * 16 + d8]);  // + self-loop
        float di = dinv[node];
        float4 bA = b1_4[d8 * 2], bB = b1_4[d8 * 2 + 1];
        ushort8v r;
        r[0] = f2bf(fmaxf(di * acc[0] + bA.x, 0.0f));
        r[1] = f2bf(fmaxf(di * acc[1] + bA.y, 0.0f));
        r[2] = f2bf(fmaxf(di * acc[2] + bA.z, 0.0f));
        r[3] = f2bf(fmaxf(di * acc[3] + bA.w, 0.0f));
        r[4] = f2bf(fmaxf(di * acc[4] + bB.x, 0.0f));
        r[5] = f2bf(fmaxf(di * acc[5] + bB.y, 0.0f));
        r[6] = f2bf(fmaxf(di * acc[6] + bB.z, 0.0f));
        r[7] = f2bf(fmaxf(di * acc[7] + bB.w, 0.0f));
        *(ushort8v*)&As[ln * KP + d8 * 8] = r;
    } else {
        *(ushort8v*)&As[ln * KP + d8 * 8] = (ushort8v)0;   // keep A-tile clean
    }
    __syncthreads();

    // phase 2: one 16-row M-tile, wave w handles col-tile w (16 cols), KS=4
    constexpr int KS = D_HID / 32;
    int w    = threadIdx.x >> 6;
    int lane = threadIdx.x & 63;
    int m = lane & 15, quad = lane >> 4;
    floatx4 acc2 = {0, 0, 0, 0};
#pragma unroll
    for (int ks = 0; ks < KS; ++ks) {
        short8 af = *(const short8*)&As[m * KP + ks * 32 + quad * 8];
        short8 bf = *(const short8*)&Wsw2[(size_t)((w * KS + ks) * 64 + lane) * 8];
        acc2 = __builtin_amdgcn_mfma_f32_16x16x32_bf16(af, bf, acc2, 0, 0, 0);
    }
#pragma unroll
    for (int reg = 0; reg < 4; ++reg) {
        int nn = nid[quad * 4 + reg];
        if (nn >= 0)
            h2[(size_t)nn * D_ENC + w * 16 + m] = f2bf(acc2[reg] * dinv[nn]);
    }
}

// ---------------- gather layer 2 + FC + sigmoid (degree-equalized via perm) ----------------
// 8 lanes per node (ushort8 over 64 ch), 32 concurrent perm slots/block, x4 chains.
__global__ void gather2_k(const ushort8v* __restrict__ hs, const int* __restrict__ rowptr,
                          const int* __restrict__ rowcnt, const int* __restrict__ srcs,
                          const float* __restrict__ dinv, const int* __restrict__ perm,
                          const float4* __restrict__ b4, const float4* __restrict__ Wfc4,
                          const float* __restrict__ bfc, float* __restrict__ out) {
    int slot = blockIdx.x * 32 + (threadIdx.x >> 3);
    int d8   = threadIdx.x & 7;
    int node = perm[slot];
    if (node < 0) return;
    int beg = rowptr[node];
    int end = beg + rowcnt[node];
    floatx8 a0 = {0,0,0,0,0,0,0,0}, a1 = a0, a2 = a0, a3 = a0;
    int i = beg;
    for (; i + 4 <= end; i += 4) {
        int s0 = srcs[i], s1 = srcs[i + 1], s2 = srcs[i + 2], s3 = srcs[i + 3];
        a0 += bf2f8(hs[(size_t)s0 * 8 + d8]);
        a1 += bf2f8(hs[(size_t)s1 * 8 + d8]);
        a2 += bf2f8(hs[(size_t)s2 * 8 + d8]);
        a3 += bf2f8(hs[(size_t)s3 * 8 + d8]);
    }
    for (; i < end; ++i)
        a0 += bf2f8(hs[(size_t)srcs[i] * 8 + d8]);
    floatx8 acc = a0 + a1 + a2 + a3 + bf2f8(hs[(size_t)node * 8 + d8]);  // + self-loop
    float di = dinv[node];
    float4 bA = b4[d8 * 2], bB = b4[d8 * 2 + 1];
    float4 wA = Wfc4[d8 * 2], wB = Wfc4[d8 * 2 + 1];
    float p = (di * acc[0] + bA.x) * wA.x + (di * acc[1] + bA.y) * wA.y
            + (di * acc[2] + bA.z) * wA.z + (di * acc[3] + bA.w) * wA.w
            + (di * acc[4] + bB.x) * wB.x + (di * acc[5] + bB.y) * wB.y
            + (di * acc[6] + bB.z) * wB.z + (di * acc[7] + bB.w) * wB.w;
#pragma unroll
    for (int off = 4; off; off >>= 1) p += __shfl_down(p, off, 8);
    if (d8 == 0) out[node] = 1.0f / (1.0f + expf(-(p + bfc[0])));
}

extern "C" void kernel_launch(void* const* d_in, const int* in_sizes, int n_in,
                              void* d_out, int out_size, void* d_ws, size_t ws_size,
                              hipStream_t stream) {
    const float* x   = (const float*)d_in[0];
    const int*   ei  = (const int*)d_in[1];     // [2, E] int32
    const float* W1  = (const float*)d_in[2];
    const float* b1  = (const float*)d_in[3];
    const float* W2  = (const float*)d_in[4];
    const float* b2  = (const float*)d_in[5];
    const float* Wfc = (const float*)d_in[6];
    const float* bfc = (const float*)d_in[7];
    float* out = (float*)d_out;

    const int* rows = ei;             // sources
    const int* cols = ei + N_EDGES;   // targets

    // workspace layout (4-byte units; 16B alignment kept for vector types)
    float* ws     = (float*)d_ws;
    float* dinv   = ws;                                   // 50048
    int*   rowptr = (int*)(ws + 50048);                   // 50048
    int*   rowcnt = rowptr + 50048;                       // 50048
    int*   perm   = rowcnt + 50048;                       // PSLOTS (50176)
    int*   bcur   = perm + PSLOTS;                        // 128
    int*   srcs   = bcur + 128;                           // NBUK*BCAP = 2M
    unsigned int* brecs = (unsigned int*)(srcs + NBUK * BCAP);     // 2M
    unsigned short* h1 = (unsigned short*)(brecs + NBUK * BCAP);   // 6.4M us
    unsigned short* h2 = h1 + (size_t)N_NODES * D_HID;             // 3.2M us
    unsigned short* Wsw1 = h2 + (size_t)N_NODES * D_ENC;           // 32768 us
    unsigned short* Wsw2 = Wsw1 + (size_t)D_IN * D_HID;            // 8192 us

    // ---- CSR build: fixed-capacity buckets; bcur = per-bucket counts ----
    hipMemsetAsync(bcur, 0, NBUK * sizeof(int), stream);
    part_k<<<(N_EDGES + 256 * PB_EPT - 1) / (256 * PB_EPT), 256, 0, stream>>>(
        rows, cols, bcur, brecs, W1, W2, Wsw1, Wsw2);
    bucket_csr_k<<<NVBUK, 512, 0, stream>>>(brecs, bcur, rowptr, rowcnt, srcs, dinv, perm);

    // ---- layer 1 GEMM ----
    gemm_mfma_k<D_IN, D_HID, false><<<(N_NODES + 63) / 64, 256, 0, stream>>>(x, Wsw1, dinv, h1, N_NODES);

    // ---- fused gather1 + gemm2 ----
    g1g2_k<<<PSLOTS / 16, 256, 0, stream>>>((const ushort8v*)h1, rowptr, rowcnt, srcs, dinv,
                                            (const float4*)b1, Wsw2, perm, h2);

    // ---- gather2 + FC + sigmoid ----
    gather2_k<<<PSLOTS / 32, 256, 0, stream>>>((const ushort8v*)h2, rowptr, rowcnt, srcs, dinv, perm,
                                               (const float4*)b2, (const float4*)Wfc,
                                               bfc, out);
}

// Round 12
// 198.570 us; speedup vs baseline: 1.0374x; 1.0374x over previous
//
#include <hip/hip_runtime.h>
#include <hip/hip_bf16.h>
#include <cmath>

#define N_NODES 50000
#define N_EDGES 800000
#define D_IN 256
#define D_HID 128
#define D_ENC 64
#define NBUK 128         // dest buckets, bucket = c >> 9 (98 used)
#define BSH 9
#define BMSK 511
#define BCAP 16384       // fixed bucket capacity (expected ~8.2K, huge margin)
#define PB_EPT 16        // edges per thread in part_k (4096/block)

typedef short short8 __attribute__((ext_vector_type(8)));
typedef float floatx4 __attribute__((ext_vector_type(4)));
typedef float floatx8 __attribute__((ext_vector_type(8)));
typedef unsigned short ushort8v __attribute__((ext_vector_type(8)));

static __device__ __forceinline__ unsigned short f2bf(float f) {
    unsigned int u = __float_as_uint(f);
    unsigned int r = (u + 0x7FFFu + ((u >> 16) & 1u)) >> 16;   // RNE
    return (unsigned short)r;
}
static __device__ __forceinline__ float bf2f(unsigned short u) {
    return __uint_as_float(((unsigned int)u) << 16);
}
static __device__ __forceinline__ floatx8 bf2f8(ushort8v u) {
    floatx8 f;
#pragma unroll
    for (int j = 0; j < 8; ++j) f[j] = bf2f(u[j]);
    return f;
}

// ---------------- W pre-swizzle into B-fragment layout (bf16) ----------------
static __device__ __forceinline__ void wswz(const float* __restrict__ W,
                                            unsigned short* __restrict__ Wsw,
                                            int t, int K, int N) {
    int KS = K / 32;
    int lane = t & 63;
    int ks   = (t >> 6) % KS;
    int ct   = (t >> 6) / KS;
    int m = lane & 15, quad = lane >> 4;
    int kbase = ks * 32 + quad * 8;
    int col   = ct * 16 + m;
#pragma unroll
    for (int j = 0; j < 8; ++j)
        Wsw[t * 8 + j] = f2bf(W[(size_t)(kbase + j) * N + col]);
}

// ---------------- radix partition: block-local counting sort + coalesced flush ----------------
// brecs rec = (src << 16) | dst (both < 65536). Bucket b occupies
// [b*BCAP, b*BCAP + count). bcur holds per-bucket COUNTS (memset 0 first).
__global__ __launch_bounds__(256) void part_k(const int* __restrict__ rows,
                                              const int* __restrict__ cols,
                                              int* __restrict__ bcur,
                                              unsigned int* __restrict__ brecs,
                                              const float* __restrict__ W1,
                                              const float* __restrict__ W2,
                                              unsigned short* __restrict__ Wsw1,
                                              unsigned short* __restrict__ Wsw2) {
    __shared__ unsigned int recs[256 * PB_EPT];   // 16 KB, bucket-grouped
    __shared__ int h[NBUK], ex[NBUK], gbase[NBUK];
    int tid = threadIdx.x;
    // fused weight swizzle on the first 20 blocks
    int t = blockIdx.x * 256 + tid;
    if (t < 4096) wswz(W1, Wsw1, t, D_IN, D_HID);
    else if (t < 5120) wswz(W2, Wsw2, t - 4096, D_HID, D_ENC);

    if (tid < NBUK) h[tid] = 0;
    __syncthreads();
    int e0 = blockIdx.x * (256 * PB_EPT);
    unsigned int myrec[PB_EPT];
    int myb[PB_EPT];
#pragma unroll
    for (int j = 0; j < PB_EPT; ++j) {
        int e = e0 + j * 256 + tid;
        if (e < N_EDGES) {
            int s = rows[e], d = cols[e];
            myrec[j] = ((unsigned int)s << 16) | (unsigned int)d;
            myb[j] = d >> BSH;
            atomicAdd(&h[myb[j]], 1);
        } else myb[j] = -1;
    }
    __syncthreads();
    // global window base per bucket (one atomic per bucket per block)
    if (tid < NBUK) {
        int c = h[tid];
        gbase[tid] = tid * BCAP + (c ? atomicAdd(&bcur[tid], c) : 0);
        ex[tid] = c;   // seed for scan
    }
    __syncthreads();
    // Hillis-Steele inclusive scan over 128 bins -> exclusive in ex
    for (int off = 1; off < NBUK; off <<= 1) {
        int v = 0;
        if (tid < NBUK && tid >= off) v = ex[tid - off];
        __syncthreads();
        if (tid < NBUK) ex[tid] += v;
        __syncthreads();
    }
    if (tid < NBUK) { ex[tid] -= h[tid]; h[tid] = 0; }   // exclusive; reset h as cursor
    __syncthreads();
    // scatter into LDS, grouped by bucket
#pragma unroll
    for (int j = 0; j < PB_EPT; ++j) {
        if (myb[j] >= 0) {
            int p = ex[myb[j]] + atomicAdd(&h[myb[j]], 1);
            recs[p] = myrec[j];
        }
    }
    __syncthreads();
    // flush: wave w copies buckets w, w+4, ... with contiguous coalesced writes
    int w = tid >> 6, lane = tid & 63;
    for (int b = w; b < NBUK; b += 4) {
        int start = ex[b], cnt = h[b], gb = gbase[b];
        int lim = (b + 1) * BCAP;   // overflow guard (never hit for this input)
        for (int i = lane; i < cnt; i += 64) {
            int gp = gb + i;
            if (gp < lim) brecs[gp] = recs[start + i];
        }
    }
}

// ---------------- per-bucket CSR: count+scan+dinv+fill, all in LDS ----------------
__global__ __launch_bounds__(512) void bucket_csr_k(const unsigned int* __restrict__ brecs,
                                                    const int* __restrict__ bcur,
                                                    int* __restrict__ rowptr,
                                                    int* __restrict__ rowcnt,
                                                    int* __restrict__ srcs,
                                                    float* __restrict__ dinv) {
    __shared__ int s[512];
    __shared__ int cur[512];
    int b = blockIdx.x;
    int cb = bcur[b]; if (cb > BCAP) cb = BCAP;
    int ebeg = b * BCAP, eend = ebeg + cb;
    int tid = threadIdx.x;
    s[tid] = 0;
    __syncthreads();
    for (int e = ebeg + tid; e < eend; e += 512)
        atomicAdd(&s[brecs[e] & BMSK], 1);   // dst low bits = local node
    __syncthreads();
    int v = s[tid];
    for (int off = 1; off < 512; off <<= 1) {
        int t = (tid >= off) ? s[tid - off] : 0;
        __syncthreads();
        s[tid] += t;
        __syncthreads();
    }
    int excl = s[tid] - v;
    cur[tid] = excl;
    int node = (b << BSH) + tid;
    if (node < N_NODES) {
        rowptr[node] = ebeg + excl;
        rowcnt[node] = v;
        dinv[node] = rsqrtf((float)(v + 1));   // +1 self-loop
    }
    __syncthreads();
    for (int e = ebeg + tid; e < eend; e += 512) {
        unsigned int rec = brecs[e];
        int p = atomicAdd(&cur[rec & BMSK], 1);
        srcs[ebeg + p] = (int)(rec >> 16);
    }
}

// ---------------- MFMA GEMM: H[r,:] = bf16(dinv[r] * (X[r,:] @ W)) ----------------
template<int K, int N, bool IN_BF16>
__global__ __launch_bounds__(256) void gemm_mfma_k(const void* __restrict__ Xv,
                                                   const unsigned short* __restrict__ Wsw,
                                                   const float* __restrict__ dinv,
                                                   unsigned short* __restrict__ H, int n) {
    constexpr int KS = K / 32, CT = N / 16, KP = K + 8;
    __shared__ unsigned short As[64 * KP];
    int row0 = blockIdx.x * 64;
    if (IN_BF16) {
        const ushort8v* X8 = (const ushort8v*)Xv;
        constexpr int NF8 = 64 * (K / 8);
        for (int idx = threadIdx.x; idx < NF8; idx += 256) {
            int r = idx / (K / 8), c8 = idx % (K / 8);
            int gr = row0 + r;
            ushort8v v = (gr < n) ? X8[(size_t)gr * (K / 8) + c8] : (ushort8v)0;
            *(ushort8v*)&As[r * KP + c8 * 8] = v;
        }
    } else {
        const float4* X4 = (const float4*)Xv;
        constexpr int NF4 = 64 * (K / 4);
        for (int idx = threadIdx.x; idx < NF4; idx += 256) {
            int r = idx / (K / 4), c4 = idx % (K / 4);
            int gr = row0 + r;
            float4 v = (gr < n) ? X4[(size_t)gr * (K / 4) + c4] : float4{0, 0, 0, 0};
            __hip_bfloat162 p0 = __float22bfloat162_rn(float2{v.x, v.y});   // packed RNE cvt
            __hip_bfloat162 p1 = __float22bfloat162_rn(float2{v.z, v.w});
            uint2 u; u.x = *(unsigned int*)&p0; u.y = *(unsigned int*)&p1;
            *(uint2*)&As[r * KP + c4 * 4] = u;
        }
    }
    __syncthreads();

    int w    = threadIdx.x >> 6;
    int lane = threadIdx.x & 63;
    int m    = lane & 15;
    int quad = lane >> 4;

    floatx4 acc[CT];
#pragma unroll
    for (int ct = 0; ct < CT; ++ct)
#pragma unroll
        for (int i = 0; i < 4; ++i) acc[ct][i] = 0.0f;

#pragma unroll
    for (int ks = 0; ks < KS; ++ks) {
        short8 af = *(const short8*)&As[(w * 16 + m) * KP + ks * 32 + quad * 8];
#pragma unroll
        for (int ct = 0; ct < CT; ++ct) {
            short8 bf = *(const short8*)&Wsw[(size_t)((ct * KS + ks) * 64 + lane) * 8];
            acc[ct] = __builtin_amdgcn_mfma_f32_16x16x32_bf16(af, bf, acc[ct], 0, 0, 0);
        }
    }

    int rbase = row0 + w * 16 + quad * 4;
    float dv[4];
#pragma unroll
    for (int reg = 0; reg < 4; ++reg) {
        int r = rbase + reg;
        dv[reg] = (r < n) ? dinv[r] : 0.0f;
    }
#pragma unroll
    for (int ct = 0; ct < CT; ++ct)
#pragma unroll
        for (int reg = 0; reg < 4; ++reg) {
            int r = rbase + reg;
            if (r < n) H[(size_t)r * N + ct * 16 + m] = f2bf(acc[ct][reg] * dv[reg]);
        }
}

// ---------------- fused gather1 + gemm2: h2 = bf16(dinv*(relu-gathered a1 @ W2)) ----------------
// Block = 256 (4 waves), 16 nodes/block processed CONCURRENTLY (16 lanes/node,
// per-lane unroll x4 chains). Rows -> LDS A-tile; phase 2: MFMA 16x128 @ 128x64.
__global__ __launch_bounds__(256) void g1g2_k(const ushort8v* __restrict__ hs,
                                              const int* __restrict__ rowptr,
                                              const int* __restrict__ rowcnt,
                                              const int* __restrict__ srcs,
                                              const float* __restrict__ dinv,
                                              const float4* __restrict__ b1_4,
                                              const unsigned short* __restrict__ Wsw2,
                                              unsigned short* __restrict__ h2) {
    constexpr int KP = D_HID + 8;   // 136
    __shared__ unsigned short As[16 * KP];
    int nodeb = blockIdx.x * 16;    // 50000 = 3125*16 exactly
    int ln = threadIdx.x >> 4;      // local node 0..15
    int d8 = threadIdx.x & 15;
    int node = nodeb + ln;
    int beg = rowptr[node];
    int end = beg + rowcnt[node];
    floatx8 a0 = {0,0,0,0,0,0,0,0}, a1 = a0, a2 = a0, a3 = a0;
    int i = beg;
    for (; i + 4 <= end; i += 4) {
        int s0 = srcs[i], s1 = srcs[i + 1], s2 = srcs[i + 2], s3 = srcs[i + 3];
        a0 += bf2f8(hs[(size_t)s0 * 16 + d8]);
        a1 += bf2f8(hs[(size_t)s1 * 16 + d8]);
        a2 += bf2f8(hs[(size_t)s2 * 16 + d8]);
        a3 += bf2f8(hs[(size_t)s3 * 16 + d8]);
    }
    for (; i < end; ++i)
        a0 += bf2f8(hs[(size_t)srcs[i] * 16 + d8]);
    floatx8 acc = a0 + a1 + a2 + a3 + bf2f8(hs[(size_t)node * 16 + d8]);  // + self-loop
    float di = dinv[node];
    float4 bA = b1_4[d8 * 2], bB = b1_4[d8 * 2 + 1];
    ushort8v r;
    r[0] = f2bf(fmaxf(di * acc[0] + bA.x, 0.0f));
    r[1] = f2bf(fmaxf(di * acc[1] + bA.y, 0.0f));
    r[2] = f2bf(fmaxf(di * acc[2] + bA.z, 0.0f));
    r[3] = f2bf(fmaxf(di * acc[3] + bA.w, 0.0f));
    r[4] = f2bf(fmaxf(di * acc[4] + bB.x, 0.0f));
    r[5] = f2bf(fmaxf(di * acc[5] + bB.y, 0.0f));
    r[6] = f2bf(fmaxf(di * acc[6] + bB.z, 0.0f));
    r[7] = f2bf(fmaxf(di * acc[7] + bB.w, 0.0f));
    *(ushort8v*)&As[ln * KP + d8 * 8] = r;
    __syncthreads();

    // phase 2: one 16-row M-tile, wave w handles col-tile w (16 cols), KS=4
    constexpr int KS = D_HID / 32;
    int w    = threadIdx.x >> 6;
    int lane = threadIdx.x & 63;
    int m = lane & 15, quad = lane >> 4;
    floatx4 acc2 = {0, 0, 0, 0};
#pragma unroll
    for (int ks = 0; ks < KS; ++ks) {
        short8 af = *(const short8*)&As[m * KP + ks * 32 + quad * 8];
        short8 bf = *(const short8*)&Wsw2[(size_t)((w * KS + ks) * 64 + lane) * 8];
        acc2 = __builtin_amdgcn_mfma_f32_16x16x32_bf16(af, bf, acc2, 0, 0, 0);
    }
#pragma unroll
    for (int reg = 0; reg < 4; ++reg) {
        int nn = nodeb + quad * 4 + reg;
        h2[(size_t)nn * D_ENC + w * 16 + m] = f2bf(acc2[reg] * dinv[nn]);
    }
}

// ---------------- gather layer 2 + FC + sigmoid ----------------
// 8 lanes per node (ushort8 over 64 ch), 32 concurrent nodes/block, x4 chains.
__global__ void gather2_k(const ushort8v* __restrict__ hs, const int* __restrict__ rowptr,
                          const int* __restrict__ rowcnt, const int* __restrict__ srcs,
                          const float* __restrict__ dinv,
                          const float4* __restrict__ b4, const float4* __restrict__ Wfc4,
                          const float* __restrict__ bfc, float* __restrict__ out) {
    int node = blockIdx.x * 32 + (threadIdx.x >> 3);
    int d8   = threadIdx.x & 7;
    if (node >= N_NODES) return;
    int beg = rowptr[node];
    int end = beg + rowcnt[node];
    floatx8 a0 = {0,0,0,0,0,0,0,0}, a1 = a0, a2 = a0, a3 = a0;
    int i = beg;
    for (; i + 4 <= end; i += 4) {
        int s0 = srcs[i], s1 = srcs[i + 1], s2 = srcs[i + 2], s3 = srcs[i + 3];
        a0 += bf2f8(hs[(size_t)s0 * 8 + d8]);
        a1 += bf2f8(hs[(size_t)s1 * 8 + d8]);
        a2 += bf2f8(hs[(size_t)s2 * 8 + d8]);
        a3 += bf2f8(hs[(size_t)s3 * 8 + d8]);
    }
    for (; i < end; ++i)
        a0 += bf2f8(hs[(size_t)srcs[i] * 8 + d8]);
    floatx8 acc = a0 + a1 + a2 + a3 + bf2f8(hs[(size_t)node * 8 + d8]);  // + self-loop
    float di = dinv[node];
    float4 bA = b4[d8 * 2], bB = b4[d8 * 2 + 1];
    float4 wA = Wfc4[d8 * 2], wB = Wfc4[d8 * 2 + 1];
    float p = (di * acc[0] + bA.x) * wA.x + (di * acc[1] + bA.y) * wA.y
            + (di * acc[2] + bA.z) * wA.z + (di * acc[3] + bA.w) * wA.w
            + (di * acc[4] + bB.x) * wB.x + (di * acc[5] + bB.y) * wB.y
            + (di * acc[6] + bB.z) * wB.z + (di * acc[7] + bB.w) * wB.w;
#pragma unroll
    for (int off = 4; off; off >>= 1) p += __shfl_down(p, off, 8);
    if (d8 == 0) out[node] = 1.0f / (1.0f + expf(-(p + bfc[0])));
}

extern "C" void kernel_launch(void* const* d_in, const int* in_sizes, int n_in,
                              void* d_out, int out_size, void* d_ws, size_t ws_size,
                              hipStream_t stream) {
    const float* x   = (const float*)d_in[0];
    const int*   ei  = (const int*)d_in[1];     // [2, E] int32
    const float* W1  = (const float*)d_in[2];
    const float* b1  = (const float*)d_in[3];
    const float* W2  = (const float*)d_in[4];
    const float* b2  = (const float*)d_in[5];
    const float* Wfc = (const float*)d_in[6];
    const float* bfc = (const float*)d_in[7];
    float* out = (float*)d_out;

    const int* rows = ei;             // sources
    const int* cols = ei + N_EDGES;   // targets

    // workspace layout (4-byte units; 16B alignment kept for vector types)
    float* ws     = (float*)d_ws;
    float* dinv   = ws;                                   // 50048
    int*   rowptr = (int*)(ws + 50048);                   // 50048
    int*   rowcnt = rowptr + 50048;                       // 50048
    int*   bcur   = rowcnt + 50048;                       // 128
    int*   srcs   = bcur + 128;                           // NBUK*BCAP = 2M
    unsigned int* brecs = (unsigned int*)(srcs + NBUK * BCAP);     // 2M
    unsigned short* h1 = (unsigned short*)(brecs + NBUK * BCAP);   // 6.4M us
    unsigned short* h2 = h1 + (size_t)N_NODES * D_HID;             // 3.2M us
    unsigned short* Wsw1 = h2 + (size_t)N_NODES * D_ENC;           // 32768 us
    unsigned short* Wsw2 = Wsw1 + (size_t)D_IN * D_HID;            // 8192 us

    // ---- CSR build: fixed-capacity buckets; bcur = per-bucket counts ----
    hipMemsetAsync(bcur, 0, NBUK * sizeof(int), stream);
    part_k<<<(N_EDGES + 256 * PB_EPT - 1) / (256 * PB_EPT), 256, 0, stream>>>(
        rows, cols, bcur, brecs, W1, W2, Wsw1, Wsw2);
    bucket_csr_k<<<(N_NODES + 511) / 512, 512, 0, stream>>>(brecs, bcur, rowptr, rowcnt, srcs, dinv);

    // ---- layer 1 GEMM ----
    gemm_mfma_k<D_IN, D_HID, false><<<(N_NODES + 63) / 64, 256, 0, stream>>>(x, Wsw1, dinv, h1, N_NODES);

    // ---- fused gather1 + gemm2 ----
    g1g2_k<<<N_NODES / 16, 256, 0, stream>>>((const ushort8v*)h1, rowptr, rowcnt, srcs, dinv,
                                             (const float4*)b1, Wsw2, h2);

    // ---- gather2 + FC + sigmoid ----
    gather2_k<<<(N_NODES + 31) / 32, 256, 0, stream>>>((const ushort8v*)h2, rowptr, rowcnt, srcs, dinv,
                                                       (const float4*)b2, (const float4*)Wfc,
                                                       bfc, out);
}

// Round 14
// 195.855 us; speedup vs baseline: 1.0518x; 1.0139x over previous
//
#include <hip/hip_runtime.h>
#include <hip/hip_bf16.h>
#include <cmath>

#define N_NODES 50000
#define N_EDGES 800000
#define D_IN 256
#define D_HID 128
#define D_ENC 64
#define NBUK 128         // dest buckets, bucket = c >> 9 (98 used)
#define BSH 9
#define BMSK 511
#define BCAP 16384       // fixed bucket capacity (expected ~8.2K, huge margin)
#define PB_EPT 16        // edges per thread in part_k (4096/block)

typedef short short8 __attribute__((ext_vector_type(8)));
typedef float floatx4 __attribute__((ext_vector_type(4)));
typedef float floatx8 __attribute__((ext_vector_type(8)));
typedef unsigned short ushort8v __attribute__((ext_vector_type(8)));

static __device__ __forceinline__ unsigned short f2bf(float f) {
    unsigned int u = __float_as_uint(f);
    unsigned int r = (u + 0x7FFFu + ((u >> 16) & 1u)) >> 16;   // RNE
    return (unsigned short)r;
}
static __device__ __forceinline__ float bf2f(unsigned short u) {
    return __uint_as_float(((unsigned int)u) << 16);
}
static __device__ __forceinline__ floatx8 bf2f8(ushort8v u) {
    floatx8 f;
#pragma unroll
    for (int j = 0; j < 8; ++j) f[j] = bf2f(u[j]);
    return f;
}

// ---------------- W pre-swizzle into B-fragment layout (bf16) ----------------
static __device__ __forceinline__ void wswz(const float* __restrict__ W,
                                            unsigned short* __restrict__ Wsw,
                                            int t, int K, int N) {
    int KS = K / 32;
    int lane = t & 63;
    int ks   = (t >> 6) % KS;
    int ct   = (t >> 6) / KS;
    int m = lane & 15, quad = lane >> 4;
    int kbase = ks * 32 + quad * 8;
    int col   = ct * 16 + m;
#pragma unroll
    for (int j = 0; j < 8; ++j)
        Wsw[t * 8 + j] = f2bf(W[(size_t)(kbase + j) * N + col]);
}

// ---------------- radix partition: block-local counting sort + coalesced flush ----------------
// brecs rec = (src << 16) | dst. Bucket b occupies [b*BCAP, b*BCAP + count).
__global__ __launch_bounds__(256) void part_k(const int* __restrict__ rows,
                                              const int* __restrict__ cols,
                                              int* __restrict__ bcur,
                                              unsigned int* __restrict__ brecs,
                                              const float* __restrict__ W1,
                                              const float* __restrict__ W2,
                                              unsigned short* __restrict__ Wsw1,
                                              unsigned short* __restrict__ Wsw2) {
    __shared__ unsigned int recs[256 * PB_EPT];   // 16 KB, bucket-grouped
    __shared__ int h[NBUK], ex[NBUK], gbase[NBUK];
    int tid = threadIdx.x;
    // fused weight swizzle on the first 20 blocks
    int t = blockIdx.x * 256 + tid;
    if (t < 4096) wswz(W1, Wsw1, t, D_IN, D_HID);
    else if (t < 5120) wswz(W2, Wsw2, t - 4096, D_HID, D_ENC);

    if (tid < NBUK) h[tid] = 0;
    __syncthreads();
    int e0 = blockIdx.x * (256 * PB_EPT);
    unsigned int myrec[PB_EPT];
    int myb[PB_EPT];
#pragma unroll
    for (int j = 0; j < PB_EPT; ++j) {
        int e = e0 + j * 256 + tid;
        if (e < N_EDGES) {
            int s = rows[e], d = cols[e];
            myrec[j] = ((unsigned int)s << 16) | (unsigned int)d;
            myb[j] = d >> BSH;
            atomicAdd(&h[myb[j]], 1);
        } else myb[j] = -1;
    }
    __syncthreads();
    if (tid < NBUK) {
        int c = h[tid];
        gbase[tid] = tid * BCAP + (c ? atomicAdd(&bcur[tid], c) : 0);
        ex[tid] = c;
    }
    __syncthreads();
    for (int off = 1; off < NBUK; off <<= 1) {
        int v = 0;
        if (tid < NBUK && tid >= off) v = ex[tid - off];
        __syncthreads();
        if (tid < NBUK) ex[tid] += v;
        __syncthreads();
    }
    if (tid < NBUK) { ex[tid] -= h[tid]; h[tid] = 0; }
    __syncthreads();
#pragma unroll
    for (int j = 0; j < PB_EPT; ++j) {
        if (myb[j] >= 0) {
            int p = ex[myb[j]] + atomicAdd(&h[myb[j]], 1);
            recs[p] = myrec[j];
        }
    }
    __syncthreads();
    int w = tid >> 6, lane = tid & 63;
    for (int b = w; b < NBUK; b += 4) {
        int start = ex[b], cnt = h[b], gb = gbase[b];
        int lim = (b + 1) * BCAP;
        for (int i = lane; i < cnt; i += 64) {
            int gp = gb + i;
            if (gp < lim) brecs[gp] = recs[start + i];
        }
    }
}

// ---------------- per-bucket CSR: count+scan+dinv+fill, all in LDS ----------------
__global__ __launch_bounds__(512) void bucket_csr_k(const unsigned int* __restrict__ brecs,
                                                    const int* __restrict__ bcur,
                                                    int* __restrict__ rowptr,
                                                    int* __restrict__ rowcnt,
                                                    unsigned short* __restrict__ srcs,
                                                    float* __restrict__ dinv) {
    __shared__ int s[512];
    __shared__ int cur[512];
    int b = blockIdx.x;
    int cb = bcur[b]; if (cb > BCAP) cb = BCAP;
    int ebeg = b * BCAP, eend = ebeg + cb;
    int tid = threadIdx.x;
    s[tid] = 0;
    __syncthreads();
    for (int e = ebeg + tid; e < eend; e += 512)
        atomicAdd(&s[brecs[e] & BMSK], 1);
    __syncthreads();
    int v = s[tid];
    for (int off = 1; off < 512; off <<= 1) {
        int t = (tid >= off) ? s[tid - off] : 0;
        __syncthreads();
        s[tid] += t;
        __syncthreads();
    }
    int excl = s[tid] - v;
    cur[tid] = excl;
    int node = (b << BSH) + tid;
    if (node < N_NODES) {
        rowptr[node] = ebeg + excl;
        rowcnt[node] = v;
        dinv[node] = rsqrtf((float)(v + 1));   // +1 self-loop
    }
    __syncthreads();
    for (int e = ebeg + tid; e < eend; e += 512) {
        unsigned int rec = brecs[e];
        int p = atomicAdd(&cur[rec & BMSK], 1);
        srcs[ebeg + p] = (unsigned short)(rec >> 16);
    }
}

// ---------------- MFMA GEMM: H[r,:] = bf16(dinv[r] * (X[r,:] @ W)) ----------------
template<int K, int N, bool IN_BF16>
__global__ __launch_bounds__(256) void gemm_mfma_k(const void* __restrict__ Xv,
                                                   const unsigned short* __restrict__ Wsw,
                                                   const float* __restrict__ dinv,
                                                   unsigned short* __restrict__ H, int n) {
    constexpr int KS = K / 32, CT = N / 16, KP = K + 8;
    __shared__ unsigned short As[64 * KP];
    int row0 = blockIdx.x * 64;
    if (IN_BF16) {
        const ushort8v* X8 = (const ushort8v*)Xv;
        constexpr int NF8 = 64 * (K / 8);
        for (int idx = threadIdx.x; idx < NF8; idx += 256) {
            int r = idx / (K / 8), c8 = idx % (K / 8);
            int gr = row0 + r;
            ushort8v v = (gr < n) ? X8[(size_t)gr * (K / 8) + c8] : (ushort8v)0;
            *(ushort8v*)&As[r * KP + c8 * 8] = v;
        }
    } else {
        const float4* X4 = (const float4*)Xv;
        constexpr int NF4 = 64 * (K / 4);
        for (int idx = threadIdx.x; idx < NF4; idx += 256) {
            int r = idx / (K / 4), c4 = idx % (K / 4);
            int gr = row0 + r;
            float4 v = (gr < n) ? X4[(size_t)gr * (K / 4) + c4] : float4{0, 0, 0, 0};
            __hip_bfloat162 p0 = __float22bfloat162_rn(float2{v.x, v.y});   // packed RNE cvt
            __hip_bfloat162 p1 = __float22bfloat162_rn(float2{v.z, v.w});
            uint2 u; u.x = *(unsigned int*)&p0; u.y = *(unsigned int*)&p1;
            *(uint2*)&As[r * KP + c4 * 4] = u;
        }
    }
    __syncthreads();

    int w    = threadIdx.x >> 6;
    int lane = threadIdx.x & 63;
    int m    = lane & 15;
    int quad = lane >> 4;

    floatx4 acc[CT];
#pragma unroll
    for (int ct = 0; ct < CT; ++ct)
#pragma unroll
        for (int i = 0; i < 4; ++i) acc[ct][i] = 0.0f;

#pragma unroll
    for (int ks = 0; ks < KS; ++ks) {
        short8 af = *(const short8*)&As[(w * 16 + m) * KP + ks * 32 + quad * 8];
#pragma unroll
        for (int ct = 0; ct < CT; ++ct) {
            short8 bf = *(const short8*)&Wsw[(size_t)((ct * KS + ks) * 64 + lane) * 8];
            acc[ct] = __builtin_amdgcn_mfma_f32_16x16x32_bf16(af, bf, acc[ct], 0, 0, 0);
        }
    }

    int rbase = row0 + w * 16 + quad * 4;
    float dv[4];
#pragma unroll
    for (int reg = 0; reg < 4; ++reg) {
        int r = rbase + reg;
        dv[reg] = (r < n) ? dinv[r] : 0.0f;
    }
#pragma unroll
    for (int ct = 0; ct < CT; ++ct)
#pragma unroll
        for (int reg = 0; reg < 4; ++reg) {
            int r = rbase + reg;
            if (r < n) H[(size_t)r * N + ct * 16 + m] = f2bf(acc[ct][reg] * dv[reg]);
        }
}

// ---------------- fused gather1 + gemm2: h2 = bf16(dinv*(relu-gathered a1 @ W2)) ----------------
// Block = 256 (4 waves), 16 nodes/block processed CONCURRENTLY (16 lanes/node,
// per-lane unroll x4 chains). Rows -> LDS A-tile; phase 2: MFMA 16x128 @ 128x64.
__global__ __launch_bounds__(256) void g1g2_k(const ushort8v* __restrict__ hs,
                                              const int* __restrict__ rowptr,
                                              const int* __restrict__ rowcnt,
                                              const unsigned short* __restrict__ srcs,
                                              const float* __restrict__ dinv,
                                              const float4* __restrict__ b1_4,
                                              const unsigned short* __restrict__ Wsw2,
                                              unsigned short* __restrict__ h2) {
    constexpr int KP = D_HID + 8;   // 136
    __shared__ unsigned short As[16 * KP];
    int nodeb = blockIdx.x * 16;    // 50000 = 3125*16 exactly
    int ln = threadIdx.x >> 4;      // local node 0..15
    int d8 = threadIdx.x & 15;
    int node = nodeb + ln;
    int beg = rowptr[node];
    int end = beg + rowcnt[node];
    floatx8 a0 = {0,0,0,0,0,0,0,0}, a1 = a0, a2 = a0, a3 = a0;
    int i = beg;
    for (; i + 4 <= end; i += 4) {
        int s0 = srcs[i], s1 = srcs[i + 1], s2 = srcs[i + 2], s3 = srcs[i + 3];
        a0 += bf2f8(hs[(size_t)s0 * 16 + d8]);
        a1 += bf2f8(hs[(size_t)s1 * 16 + d8]);
        a2 += bf2f8(hs[(size_t)s2 * 16 + d8]);
        a3 += bf2f8(hs[(size_t)s3 * 16 + d8]);
    }
    for (; i < end; ++i)
        a0 += bf2f8(hs[(size_t)srcs[i] * 16 + d8]);
    floatx8 acc = a0 + a1 + a2 + a3 + bf2f8(hs[(size_t)node * 16 + d8]);  // + self-loop
    float di = dinv[node];
    float4 bA = b1_4[d8 * 2], bB = b1_4[d8 * 2 + 1];
    ushort8v r;
    r[0] = f2bf(fmaxf(di * acc[0] + bA.x, 0.0f));
    r[1] = f2bf(fmaxf(di * acc[1] + bA.y, 0.0f));
    r[2] = f2bf(fmaxf(di * acc[2] + bA.z, 0.0f));
    r[3] = f2bf(fmaxf(di * acc[3] + bA.w, 0.0f));
    r[4] = f2bf(fmaxf(di * acc[4] + bB.x, 0.0f));
    r[5] = f2bf(fmaxf(di * acc[5] + bB.y, 0.0f));
    r[6] = f2bf(fmaxf(di * acc[6] + bB.z, 0.0f));
    r[7] = f2bf(fmaxf(di * acc[7] + bB.w, 0.0f));
    *(ushort8v*)&As[ln * KP + d8 * 8] = r;
    __syncthreads();

    // phase 2: one 16-row M-tile, wave w handles col-tile w (16 cols), KS=4
    constexpr int KS = D_HID / 32;
    int w    = threadIdx.x >> 6;
    int lane = threadIdx.x & 63;
    int m = lane & 15, quad = lane >> 4;
    floatx4 acc2 = {0, 0, 0, 0};
#pragma unroll
    for (int ks = 0; ks < KS; ++ks) {
        short8 af = *(const short8*)&As[m * KP + ks * 32 + quad * 8];
        short8 bf = *(const short8*)&Wsw2[(size_t)((w * KS + ks) * 64 + lane) * 8];
        acc2 = __builtin_amdgcn_mfma_f32_16x16x32_bf16(af, bf, acc2, 0, 0, 0);
    }
#pragma unroll
    for (int reg = 0; reg < 4; ++reg) {
        int nn = nodeb + quad * 4 + reg;
        h2[(size_t)nn * D_ENC + w * 16 + m] = f2bf(acc2[reg] * dinv[nn]);
    }
}

// ---------------- gather layer 2 + FC + sigmoid ----------------
// 8 lanes per node (ushort8 over 64 ch), 32 concurrent nodes/block, x4 chains.
__global__ void gather2_k(const ushort8v* __restrict__ hs, const int* __restrict__ rowptr,
                          const int* __restrict__ rowcnt, const unsigned short* __restrict__ srcs,
                          const float* __restrict__ dinv,
                          const float4* __restrict__ b4, const float4* __restrict__ Wfc4,
                          const float* __restrict__ bfc, float* __restrict__ out) {
    int node = blockIdx.x * 32 + (threadIdx.x >> 3);
    int d8   = threadIdx.x & 7;
    if (node >= N_NODES) return;
    int beg = rowptr[node];
    int end = beg + rowcnt[node];
    floatx8 a0 = {0,0,0,0,0,0,0,0}, a1 = a0, a2 = a0, a3 = a0;
    int i = beg;
    for (; i + 4 <= end; i += 4) {
        int s0 = srcs[i], s1 = srcs[i + 1], s2 = srcs[i + 2], s3 = srcs[i + 3];
        a0 += bf2f8(hs[(size_t)s0 * 8 + d8]);
        a1 += bf2f8(hs[(size_t)s1 * 8 + d8]);
        a2 += bf2f8(hs[(size_t)s2 * 8 + d8]);
        a3 += bf2f8(hs[(size_t)s3 * 8 + d8]);
    }
    for (; i < end; ++i)
        a0 += bf2f8(hs[(size_t)srcs[i] * 8 + d8]);
    floatx8 acc = a0 + a1 + a2 + a3 + bf2f8(hs[(size_t)node * 8 + d8]);  // + self-loop
    float di = dinv[node];
    float4 bA = b4[d8 * 2], bB = b4[d8 * 2 + 1];
    float4 wA = Wfc4[d8 * 2], wB = Wfc4[d8 * 2 + 1];
    float p = (di * acc[0] + bA.x) * wA.x + (di * acc[1] + bA.y) * wA.y
            + (di * acc[2] + bA.z) * wA.z + (di * acc[3] + bA.w) * wA.w
            + (di * acc[4] + bB.x) * wB.x + (di * acc[5] + bB.y) * wB.y
            + (di * acc[6] + bB.z) * wB.z + (di * acc[7] + bB.w) * wB.w;
#pragma unroll
    for (int off = 4; off; off >>= 1) p += __shfl_down(p, off, 8);
    if (d8 == 0) out[node] = 1.0f / (1.0f + expf(-(p + bfc[0])));
}

extern "C" void kernel_launch(void* const* d_in, const int* in_sizes, int n_in,
                              void* d_out, int out_size, void* d_ws, size_t ws_size,
                              hipStream_t stream) {
    const float* x   = (const float*)d_in[0];
    const int*   ei  = (const int*)d_in[1];     // [2, E] int32
    const float* W1  = (const float*)d_in[2];
    const float* b1  = (const float*)d_in[3];
    const float* W2  = (const float*)d_in[4];
    const float* b2  = (const float*)d_in[5];
    const float* Wfc = (const float*)d_in[6];
    const float* bfc = (const float*)d_in[7];
    float* out = (float*)d_out;

    const int* rows = ei;             // sources
    const int* cols = ei + N_EDGES;   // targets

    // workspace layout (16B alignment kept for vector types)
    float* ws     = (float*)d_ws;
    float* dinv   = ws;                                   // 50048
    int*   rowptr = (int*)(ws + 50048);                   // 50048
    int*   rowcnt = rowptr + 50048;                       // 50048
    int*   bcur   = rowcnt + 50048;                       // 128
    unsigned int* brecs = (unsigned int*)(bcur + 128);    // NBUK*BCAP u32 (8MB)
    unsigned short* srcs = (unsigned short*)(brecs + NBUK * BCAP);  // NBUK*BCAP u16 (4MB)
    unsigned short* h1 = srcs + (size_t)NBUK * BCAP;               // 6.4M us
    unsigned short* h2 = h1 + (size_t)N_NODES * D_HID;             // 3.2M us
    unsigned short* Wsw1 = h2 + (size_t)N_NODES * D_ENC;           // 32768 us
    unsigned short* Wsw2 = Wsw1 + (size_t)D_IN * D_HID;            // 8192 us

    // ---- CSR build: fixed-capacity buckets; bcur = per-bucket counts ----
    hipMemsetAsync(bcur, 0, NBUK * sizeof(int), stream);
    part_k<<<(N_EDGES + 256 * PB_EPT - 1) / (256 * PB_EPT), 256, 0, stream>>>(
        rows, cols, bcur, brecs, W1, W2, Wsw1, Wsw2);
    bucket_csr_k<<<(N_NODES + 511) / 512, 512, 0, stream>>>(brecs, bcur, rowptr, rowcnt, srcs, dinv);

    // ---- layer 1 GEMM ----
    gemm_mfma_k<D_IN, D_HID, false><<<(N_NODES + 63) / 64, 256, 0, stream>>>(x, Wsw1, dinv, h1, N_NODES);

    // ---- fused gather1 + gemm2 ----
    g1g2_k<<<N_NODES / 16, 256, 0, stream>>>((const ushort8v*)h1, rowptr, rowcnt, srcs, dinv,
                                             (const float4*)b1, Wsw2, h2);

    // ---- gather2 + FC + sigmoid ----
    gather2_k<<<(N_NODES + 31) / 32, 256, 0, stream>>>((const ushort8v*)h2, rowptr, rowcnt, srcs, dinv,
                                                       (const float4*)b2, (const float4*)Wfc,
                                                       bfc, out);
}